// Round 19
// baseline (213.663 us; speedup 1.0000x reference)
//
#include <hip/hip_runtime.h>
#include <hip/hip_bf16.h>

// Fused span-pair + attention-pooling model for MI355X (gfx950).
// B=8, N=128, H=768, C=5, P = N(N+1)/2 = 8256.
// R19 = R18 (161.6us) + s_setprio(1) around the MFMA cluster ONLY
//       (single-change A/B; R14 bundled it with coef changes and spilled).

#define B_ 8
#define N_ 128
#define H_ 768
#define C_ 5
#define P_ 8256
#define TP 64
#define NBLK 129     // P_/TP
#define NSTEP 24     // K steps of 32

typedef short bf16x8 __attribute__((ext_vector_type(8)));
typedef float f32x4 __attribute__((ext_vector_type(4)));

__device__ __forceinline__ float bf2f(unsigned short u){
  union { unsigned u; float f; } v; v.u = ((unsigned)u) << 16; return v.f;
}
__device__ __forceinline__ unsigned short f2bf(float f){
  union { float f; unsigned u; } v; v.f = f;
  unsigned r = v.u + 0x7FFFu + ((v.u >> 16) & 1u);
  return (unsigned short)(r >> 16);
}
__device__ __forceinline__ float tanh_fast(float x){
  float e = __expf(2.f * x);
  return 1.f - 2.f / (e + 1.f);
}
// bf16 product pack via v_cvt_pk_bf16_f32 (RNE, 1 instr per 2 elems)
__device__ __forceinline__ bf16x8 prodpack(bf16x8 x, bf16x8 y){
  union { bf16x8 v; unsigned u[4]; } o;
  #pragma unroll
  for (int e2 = 0; e2 < 4; e2++){
    float p0 = bf2f((unsigned short)x[e2*2])   * bf2f((unsigned short)y[e2*2]);
    float p1 = bf2f((unsigned short)x[e2*2+1]) * bf2f((unsigned short)y[e2*2+1]);
    unsigned pk;
    asm volatile("v_cvt_pk_bf16_f32 %0, %1, %2" : "=v"(pk) : "v"(p0), "v"(p1));
    o.u[e2] = pk;
  }
  return o.v;
}
// swizzled LDS byte offset for a [rows][768] bf16 panel; row stride 1536B.
// XOR bits 4..7 with row: verified conflict-free (R5-R18: SQ_LDS_BANK_CONFLICT=0).
__device__ __forceinline__ int lds_off(int row, int k){
  return row * (H_ * 2) + ((k * 2) ^ ((row & 15) << 4));
}

// ---------------- prep: pack_h + pack_weights + pairs fused ----------------

#define PH_BLKS 3072   // 786432/256
#define PW_BLKS 288    // 73728/256
#define PR_BLKS 33     // ceil(8256/256)

__global__ void prep(const float* __restrict__ h, const float* __restrict__ Wcat,
                     unsigned short* __restrict__ hb,
                     unsigned short* __restrict__ Wsum,
                     unsigned short* __restrict__ Wdif,
                     unsigned short* __restrict__ W4s,
                     int* __restrict__ ii, int* __restrict__ jj){
  const int bid = blockIdx.x;
  if (bid < PH_BLKS){
    int idx = bid * 256 + threadIdx.x;
    hb[idx] = f2bf(h[idx]);
  } else if (bid < PH_BLKS + PW_BLKS){
    int idx = (bid - PH_BLKS) * 256 + threadIdx.x;   // < 96*768
    int o = idx / H_, col = idx % H_;
    bf16x8 vs, vd, v4;
    #pragma unroll
    for (int e = 0; e < 8; e++){
      int hrow = o * 8 + e;
      float w1 = Wcat[hrow * H_ + col];
      float w2 = Wcat[(H_ + hrow) * H_ + col];
      float w3 = Wcat[(2 * H_ + hrow) * H_ + col];
      float w4 = Wcat[(3 * H_ + hrow) * H_ + col];
      vs[e] = (short)f2bf(w1 + w3);
      vd[e] = (short)f2bf(w2 - w3);
      v4[e] = (short)f2bf(w4);
    }
    int pbase = (o * H_ + col) * 8;
    *(bf16x8*)(Wsum + pbase) = vs;
    *(bf16x8*)(Wdif + pbase) = vd;
    *(bf16x8*)(W4s + pbase)  = v4;
  } else {
    int p = (bid - PH_BLKS - PW_BLKS) * 256 + threadIdx.x;
    if (p < P_){
      int i = 0, off = 0;
      while (off + (N_ - i) <= p){ off += (N_ - i); i++; }
      ii[p] = i; jj[p] = i + (p - off);
    }
  }
}

// ---------------- phase 1: Acoef = h@(W1+W3)+bW, Bcoef = h@(W2-W3) ----------------
// col-split x2: 256 blocks (full machine), each streams 0.56MB of W.

__global__ __launch_bounds__(512, 4) void coef_gemm(
    const unsigned short* __restrict__ hb,
    const unsigned short* __restrict__ Wsum,
    const unsigned short* __restrict__ Wdif,
    const float* __restrict__ bW,
    float* __restrict__ Acoef, float* __restrict__ Bcoef){
  const int sel = blockIdx.y;                 // 0 -> Acoef, 1 -> Bcoef
  const int chalf = blockIdx.z;               // 0/1 : 384-col half
  const unsigned short* Wp = sel ? Wdif : Wsum;
  float* out = sel ? Bcoef : Acoef;
  const int growb = blockIdx.x * 16;          // 16 rows of the 1024 flat rows

  __shared__ char As[16 * H_ * 2];            // 24 KiB swizzled bf16 panel

  const int tid = threadIdx.x;
  { // stage 16 hb rows, k-interleaved
    int r = tid >> 5;          // 0..15
    int c = tid & 31;          // 0..31
    const unsigned short* src = hb + (growb + r) * H_;
    #pragma unroll
    for (int kk = 0; kk < 3; kk++){
      int k = kk * 256 + c * 8;
      bf16x8 v = *(const bf16x8*)(src + k);
      *(bf16x8*)(As + lds_off(r, k)) = v;
    }
  }
  __syncthreads();

  const int lane = tid & 63;
  const int wn = tid >> 6;      // 0..7 : 48-col group within the half
  const int hi = lane >> 4;     // 0..3
  const int l15 = lane & 15;
  const int colbase = chalf * 384 + wn * 48 + l15;

  f32x4 acc[3] = {};

  const bf16x8* wp = (const bf16x8*)Wp + hi * H_ + colbase;
  bf16x8 bc0 = wp[0], bc1 = wp[16], bc2 = wp[32];
  wp += 4 * H_;
  for (int step = 0; step < 24; ++step){
    bf16x8 bn0 = wp[0], bn1 = wp[16], bn2 = wp[32];
    wp += 4 * H_;   // last iter reads past Wp into adjacent ws region: safe, discarded
    bf16x8 a = *(const bf16x8*)(As + lds_off(l15, step * 32 + hi * 8));
    acc[0] = __builtin_amdgcn_mfma_f32_16x16x32_bf16(a, bc0, acc[0], 0, 0, 0);
    acc[1] = __builtin_amdgcn_mfma_f32_16x16x32_bf16(a, bc1, acc[1], 0, 0, 0);
    acc[2] = __builtin_amdgcn_mfma_f32_16x16x32_bf16(a, bc2, acc[2], 0, 0, 0);
    bc0 = bn0; bc1 = bn1; bc2 = bn2;
  }

  #pragma unroll
  for (int ni = 0; ni < 3; ni++){
    int col = colbase + ni * 16;
    float bw = (sel == 0) ? bW[col] : 0.f;
    #pragma unroll
    for (int r = 0; r < 4; r++){
      int grow = growb + hi * 4 + r;
      out[grow * H_ + col] = acc[ni][r] + bw;
    }
  }
}

// ---------------- phase 2: fused span GEMM + tanh + online softmax-pool ----------------
// R15/R18 structure verbatim + s_setprio around the MFMA cluster (T5;
// barrier-free K-loop -> waves at diverse phases -> scheduler can favor
// MFMA-entering waves).

__global__ __launch_bounds__(1024, 4)
void spans_fused(
    const unsigned short* __restrict__ hb,
    const float* __restrict__ Acoef,
    const float* __restrict__ Bcoef,
    const unsigned short* __restrict__ W4s,
    const float* __restrict__ hhat,
    const int* __restrict__ ii,
    const int* __restrict__ jj,
    float* __restrict__ pm, float* __restrict__ pl, float* __restrict__ pacc){
  __shared__ char As[TP * H_ * 2];       // 96 KiB swizzled product panel
  __shared__ int iis[TP], jjs[TP];
  __shared__ float sbuf[16][TP];
  __shared__ float wbuf[TP];

  const int bidraw = blockIdx.x;
  const int b = bidraw & 7;              // batch -> XCD affinity (scalar remap)
  const int tile = bidraw >> 3;          // 0..128
  const int bid = b * NBLK + tile;       // logical id for pm/pl/pacc
  const int p0 = tile * TP;
  const int tid = threadIdx.x;

  if (tid < TP){ iis[tid] = ii[p0 + tid]; jjs[tid] = jj[p0 + tid]; }
  __syncthreads();

  { // stage products h_i (.) h_j (bf16), k-interleaved: k = kk*128 + c*8
    int r = tid >> 4;      // 0..63 pair row
    int c = tid & 15;      // 0..15
    const unsigned short* hp = hb + (b * N_ + iis[r]) * H_;
    const unsigned short* hq = hb + (b * N_ + jjs[r]) * H_;
    #pragma unroll
    for (int kk = 0; kk < 6; kk++){
      int k = kk * 128 + c * 8;
      bf16x8 va = *(const bf16x8*)(hp + k);
      bf16x8 vb = *(const bf16x8*)(hq + k);
      *(bf16x8*)(As + lds_off(r, k)) = prodpack(va, vb);
    }
  }

  const int lane = tid & 63;
  const int wave = tid >> 6;     // 0..15 : 48-col group
  const int hi = lane >> 4;      // 0..3
  const int l15 = lane & 15;
  const int colbase = wave * 48 + l15;

  // accumulator init = Acoef[i,col] + Bcoef[j,col]  (MFMA C-in; overlaps staging)
  f32x4 acc[4][3];
  #pragma unroll
  for (int mi = 0; mi < 4; mi++){
    #pragma unroll
    for (int r = 0; r < 4; r++){
      int rowl = mi * 16 + hi * 4 + r;
      const float* ap = Acoef + (b * N_ + iis[rowl]) * H_ + colbase;
      const float* bp = Bcoef + (b * N_ + jjs[rowl]) * H_ + colbase;
      #pragma unroll
      for (int ni = 0; ni < 3; ni++)
        acc[mi][ni][r] = ap[ni * 16] + bp[ni * 16];
    }
  }

  // 3-slot B pipeline prologue: load steps 0 and 1
  const bf16x8* wp = (const bf16x8*)W4s + hi * H_ + colbase;
  bf16x8 bs[3][3];
  #pragma unroll
  for (int s = 0; s < 2; s++)
    #pragma unroll
    for (int ni = 0; ni < 3; ni++)
      bs[s][ni] = wp[s * 4 * H_ + ni * 16];

  __syncthreads();

  // ---- main K loop: fully unrolled so bs[t%3] indices are compile-time
  #pragma unroll
  for (int t = 0; t < NSTEP; ++t){
    // issue B loads for step t+2 (lead 2)
    if (t + 2 < NSTEP){
      #pragma unroll
      for (int ni = 0; ni < 3; ni++)
        bs[(t + 2) % 3][ni] = wp[(t + 2) * 4 * H_ + ni * 16];
    }
    const int kb = t * 32 + hi * 8;
    bf16x8 a0 = *(const bf16x8*)(As + lds_off(     l15, kb));
    bf16x8 a1 = *(const bf16x8*)(As + lds_off(16 + l15, kb));
    bf16x8 a2 = *(const bf16x8*)(As + lds_off(32 + l15, kb));
    bf16x8 a3 = *(const bf16x8*)(As + lds_off(48 + l15, kb));
    __builtin_amdgcn_s_setprio(1);
    #pragma unroll
    for (int ni = 0; ni < 3; ni++){
      bf16x8 bfr = bs[t % 3][ni];
      acc[0][ni] = __builtin_amdgcn_mfma_f32_16x16x32_bf16(a0, bfr, acc[0][ni], 0, 0, 0);
      acc[1][ni] = __builtin_amdgcn_mfma_f32_16x16x32_bf16(a1, bfr, acc[1][ni], 0, 0, 0);
      acc[2][ni] = __builtin_amdgcn_mfma_f32_16x16x32_bf16(a2, bfr, acc[2][ni], 0, 0, 0);
      acc[3][ni] = __builtin_amdgcn_mfma_f32_16x16x32_bf16(a3, bfr, acc[3][ni], 0, 0, 0);
    }
    __builtin_amdgcn_s_setprio(0);
  }

  // epilogue (pure VALU): spans = tanh(acc); score partials vs h_hat
  float sc[4][4];
  #pragma unroll
  for (int mi = 0; mi < 4; mi++)
    #pragma unroll
    for (int r = 0; r < 4; r++) sc[mi][r] = 0.f;

  #pragma unroll
  for (int ni = 0; ni < 3; ni++){
    float hh = hhat[colbase + ni * 16];
    #pragma unroll
    for (int mi = 0; mi < 4; mi++){
      #pragma unroll
      for (int r = 0; r < 4; r++){
        float s = tanh_fast(acc[mi][ni][r]);
        acc[mi][ni][r] = s;            // keep span in-register
        sc[mi][r] += s * hh;
      }
    }
  }
  // reduce score over the 16-lane column group
  #pragma unroll
  for (int mi = 0; mi < 4; mi++)
    #pragma unroll
    for (int r = 0; r < 4; r++){
      float v = sc[mi][r];
      v += __shfl_xor(v, 1); v += __shfl_xor(v, 2);
      v += __shfl_xor(v, 4); v += __shfl_xor(v, 8);
      sc[mi][r] = v;
    }
  if (l15 == 0){
    #pragma unroll
    for (int mi = 0; mi < 4; mi++)
      #pragma unroll
      for (int r = 0; r < 4; r++)
        sbuf[wave][mi * 16 + hi * 4 + r] = sc[mi][r];
  }
  __syncthreads();

  // block-local softmax weights (wave 0)
  if (tid < TP){
    float s = 0.f;
    #pragma unroll
    for (int w = 0; w < 16; w++) s += sbuf[w][tid];
    float m = s;
    #pragma unroll
    for (int off = 1; off < 64; off <<= 1) m = fmaxf(m, __shfl_xor(m, off));
    float w = __expf(s - m);
    float l = w;
    #pragma unroll
    for (int off = 1; off < 64; off <<= 1) l += __shfl_xor(l, off);
    wbuf[tid] = w;
    if (tid == 0){ pm[bid] = m; pl[bid] = l; }
  }
  __syncthreads();

  // weighted span accumulation -> pacc directly
  #pragma unroll
  for (int ni = 0; ni < 3; ni++){
    float wa = 0.f;
    #pragma unroll
    for (int mi = 0; mi < 4; mi++)
      #pragma unroll
      for (int r = 0; r < 4; r++){
        int rowl = mi * 16 + hi * 4 + r;
        wa += wbuf[rowl] * acc[mi][ni][r];
      }
    wa += __shfl_xor(wa, 16);
    wa += __shfl_xor(wa, 32);
    if (lane < 16) pacc[bid * H_ + colbase + ni * 16] = wa;
  }
}

// ---------------- phase 3: fused flash-merge + logits + log_softmax ----------------

__global__ void merge_kernel(
    const float* __restrict__ pm, const float* __restrict__ pl,
    const float* __restrict__ pacc,
    const float* __restrict__ Wout, const float* __restrict__ bout,
    float* __restrict__ outp){
  __shared__ float ebuf[NBLK];
  __shared__ float ht[H_];
  __shared__ float MLs[2];
  __shared__ float lg[C_];
  const int b = blockIdx.x;
  const int tid = threadIdx.x;   // 768

  if (tid < 64){
    float m = -3.4e38f;
    for (int t = tid; t < NBLK; t += 64) m = fmaxf(m, pm[b * NBLK + t]);
    #pragma unroll
    for (int off = 1; off < 64; off <<= 1) m = fmaxf(m, __shfl_xor(m, off));
    float l = 0.f;
    for (int t = tid; t < NBLK; t += 64) l += pl[b * NBLK + t] * __expf(pm[b * NBLK + t] - m);
    #pragma unroll
    for (int off = 1; off < 64; off <<= 1) l += __shfl_xor(l, off);
    if (tid == 0){ MLs[0] = m; MLs[1] = 1.f / l; }
  }
  __syncthreads();
  const float M = MLs[0], invL = MLs[1];
  if (tid < NBLK) ebuf[tid] = __expf(pm[b * NBLK + tid] - M);
  __syncthreads();
  { // one column per thread, coalesced pacc rows
    float a = 0.f;
    for (int t = 0; t < NBLK; t++) a += pacc[(b * NBLK + t) * H_ + tid] * ebuf[t];
    ht[tid] = a * invL;
  }
  __syncthreads();
  if (tid < C_ * 64){
    int c = tid >> 6; int lane = tid & 63;
    float a = 0.f;
    for (int k = lane; k < H_; k += 64) a += ht[k] * Wout[k * C_ + c];
    #pragma unroll
    for (int off = 1; off < 64; off <<= 1) a += __shfl_xor(a, off);
    if (lane == 0) lg[c] = a + bout[c];
  }
  __syncthreads();
  if (tid == 0){
    float mx = lg[0];
    #pragma unroll
    for (int c = 1; c < C_; c++) mx = fmaxf(mx, lg[c]);
    float s = 0.f;
    #pragma unroll
    for (int c = 0; c < C_; c++) s += __expf(lg[c] - mx);
    float ls = __logf(s) + mx;
    #pragma unroll
    for (int c = 0; c < C_; c++) outp[b * C_ + c] = lg[c] - ls;
  }
}

// ---------------- launch ----------------

extern "C" void kernel_launch(void* const* d_in, const int* in_sizes, int n_in,
                              void* d_out, int out_size, void* d_ws, size_t ws_size,
                              hipStream_t stream){
  const float* h    = (const float*)d_in[0];
  const float* Wcat = (const float*)d_in[1];
  const float* bW   = (const float*)d_in[2];
  const float* hhat = (const float*)d_in[3];
  const float* Wout = (const float*)d_in[4];
  const float* bout = (const float*)d_in[5];
  float* outp = (float*)d_out;

  // workspace carve-up (~14.7 MB total)
  unsigned short* hb   = (unsigned short*)d_ws;        // 786432 bf16
  unsigned short* Wsum = hb + 786432;                  // 589824 bf16 each
  unsigned short* Wdif = Wsum + 589824;
  unsigned short* W4s  = Wdif + 589824;
  float* Acoef = (float*)(W4s + 589824);               // 786432 f32
  float* Bcoef = Acoef + 786432;                       // 786432 f32
  int* iiA = (int*)(Bcoef + 786432);                   // 8256 i32
  int* jjA = iiA + P_;
  float* pm = (float*)(jjA + P_);                      // 1032 f32
  float* pl = pm + (B_ * NBLK);
  float* pacc = pl + (B_ * NBLK);                      // 1032*768 f32

  prep<<<PH_BLKS + PW_BLKS + PR_BLKS, 256, 0, stream>>>(h, Wcat, hb, Wsum, Wdif, W4s, iiA, jjA);
  coef_gemm<<<dim3(64, 2, 2), 512, 0, stream>>>(hb, Wsum, Wdif, bW, Acoef, Bcoef);
  spans_fused<<<B_ * NBLK, 1024, 0, stream>>>(hb, Acoef, Bcoef, W4s, hhat, iiA, jjA, pm, pl, pacc);
  merge_kernel<<<B_, 768, 0, stream>>>(pm, pl, pacc, Wout, bout, outp);
}

// Round 20
// 161.299 us; speedup vs baseline: 1.3246x; 1.3246x over previous
//
#include <hip/hip_runtime.h>
#include <hip/hip_bf16.h>

// Fused span-pair + attention-pooling model for MI355X (gfx950).
// B=8, N=128, H=768, C=5, P = N(N+1)/2 = 8256.
// R20 = R18 verbatim (161.6us session best). R19's setprio-only change
// spilled (6th strike: ANY K-loop body addition tips regalloc at 1024 thr).
// spans_fused is at its serial-sum-of-pipes structural limit; all overlap
// mechanisms counter-tested R2-R19 null or regress.

#define B_ 8
#define N_ 128
#define H_ 768
#define C_ 5
#define P_ 8256
#define TP 64
#define NBLK 129     // P_/TP
#define NSTEP 24     // K steps of 32

typedef short bf16x8 __attribute__((ext_vector_type(8)));
typedef float f32x4 __attribute__((ext_vector_type(4)));

__device__ __forceinline__ float bf2f(unsigned short u){
  union { unsigned u; float f; } v; v.u = ((unsigned)u) << 16; return v.f;
}
__device__ __forceinline__ unsigned short f2bf(float f){
  union { float f; unsigned u; } v; v.f = f;
  unsigned r = v.u + 0x7FFFu + ((v.u >> 16) & 1u);
  return (unsigned short)(r >> 16);
}
__device__ __forceinline__ float tanh_fast(float x){
  float e = __expf(2.f * x);
  return 1.f - 2.f / (e + 1.f);
}
// bf16 product pack via v_cvt_pk_bf16_f32 (RNE, 1 instr per 2 elems)
__device__ __forceinline__ bf16x8 prodpack(bf16x8 x, bf16x8 y){
  union { bf16x8 v; unsigned u[4]; } o;
  #pragma unroll
  for (int e2 = 0; e2 < 4; e2++){
    float p0 = bf2f((unsigned short)x[e2*2])   * bf2f((unsigned short)y[e2*2]);
    float p1 = bf2f((unsigned short)x[e2*2+1]) * bf2f((unsigned short)y[e2*2+1]);
    unsigned pk;
    asm volatile("v_cvt_pk_bf16_f32 %0, %1, %2" : "=v"(pk) : "v"(p0), "v"(p1));
    o.u[e2] = pk;
  }
  return o.v;
}
// swizzled LDS byte offset for a [rows][768] bf16 panel; row stride 1536B.
// XOR bits 4..7 with row: verified conflict-free (R5-R18: SQ_LDS_BANK_CONFLICT=0).
__device__ __forceinline__ int lds_off(int row, int k){
  return row * (H_ * 2) + ((k * 2) ^ ((row & 15) << 4));
}

// ---------------- prep: pack_h + pack_weights + pairs fused ----------------

#define PH_BLKS 3072   // 786432/256
#define PW_BLKS 288    // 73728/256
#define PR_BLKS 33     // ceil(8256/256)

__global__ void prep(const float* __restrict__ h, const float* __restrict__ Wcat,
                     unsigned short* __restrict__ hb,
                     unsigned short* __restrict__ Wsum,
                     unsigned short* __restrict__ Wdif,
                     unsigned short* __restrict__ W4s,
                     int* __restrict__ ii, int* __restrict__ jj){
  const int bid = blockIdx.x;
  if (bid < PH_BLKS){
    int idx = bid * 256 + threadIdx.x;
    hb[idx] = f2bf(h[idx]);
  } else if (bid < PH_BLKS + PW_BLKS){
    int idx = (bid - PH_BLKS) * 256 + threadIdx.x;   // < 96*768
    int o = idx / H_, col = idx % H_;
    bf16x8 vs, vd, v4;
    #pragma unroll
    for (int e = 0; e < 8; e++){
      int hrow = o * 8 + e;
      float w1 = Wcat[hrow * H_ + col];
      float w2 = Wcat[(H_ + hrow) * H_ + col];
      float w3 = Wcat[(2 * H_ + hrow) * H_ + col];
      float w4 = Wcat[(3 * H_ + hrow) * H_ + col];
      vs[e] = (short)f2bf(w1 + w3);
      vd[e] = (short)f2bf(w2 - w3);
      v4[e] = (short)f2bf(w4);
    }
    int pbase = (o * H_ + col) * 8;
    *(bf16x8*)(Wsum + pbase) = vs;
    *(bf16x8*)(Wdif + pbase) = vd;
    *(bf16x8*)(W4s + pbase)  = v4;
  } else {
    int p = (bid - PH_BLKS - PW_BLKS) * 256 + threadIdx.x;
    if (p < P_){
      int i = 0, off = 0;
      while (off + (N_ - i) <= p){ off += (N_ - i); i++; }
      ii[p] = i; jj[p] = i + (p - off);
    }
  }
}

// ---------------- phase 1: Acoef = h@(W1+W3)+bW, Bcoef = h@(W2-W3) ----------------
// col-split x2: 256 blocks (full machine), each streams 0.56MB of W.

__global__ __launch_bounds__(512, 4) void coef_gemm(
    const unsigned short* __restrict__ hb,
    const unsigned short* __restrict__ Wsum,
    const unsigned short* __restrict__ Wdif,
    const float* __restrict__ bW,
    float* __restrict__ Acoef, float* __restrict__ Bcoef){
  const int sel = blockIdx.y;                 // 0 -> Acoef, 1 -> Bcoef
  const int chalf = blockIdx.z;               // 0/1 : 384-col half
  const unsigned short* Wp = sel ? Wdif : Wsum;
  float* out = sel ? Bcoef : Acoef;
  const int growb = blockIdx.x * 16;          // 16 rows of the 1024 flat rows

  __shared__ char As[16 * H_ * 2];            // 24 KiB swizzled bf16 panel

  const int tid = threadIdx.x;
  { // stage 16 hb rows, k-interleaved
    int r = tid >> 5;          // 0..15
    int c = tid & 31;          // 0..31
    const unsigned short* src = hb + (growb + r) * H_;
    #pragma unroll
    for (int kk = 0; kk < 3; kk++){
      int k = kk * 256 + c * 8;
      bf16x8 v = *(const bf16x8*)(src + k);
      *(bf16x8*)(As + lds_off(r, k)) = v;
    }
  }
  __syncthreads();

  const int lane = tid & 63;
  const int wn = tid >> 6;      // 0..7 : 48-col group within the half
  const int hi = lane >> 4;     // 0..3
  const int l15 = lane & 15;
  const int colbase = chalf * 384 + wn * 48 + l15;

  f32x4 acc[3] = {};

  const bf16x8* wp = (const bf16x8*)Wp + hi * H_ + colbase;
  bf16x8 bc0 = wp[0], bc1 = wp[16], bc2 = wp[32];
  wp += 4 * H_;
  for (int step = 0; step < 24; ++step){
    bf16x8 bn0 = wp[0], bn1 = wp[16], bn2 = wp[32];
    wp += 4 * H_;   // last iter reads past Wp into adjacent ws region: safe, discarded
    bf16x8 a = *(const bf16x8*)(As + lds_off(l15, step * 32 + hi * 8));
    acc[0] = __builtin_amdgcn_mfma_f32_16x16x32_bf16(a, bc0, acc[0], 0, 0, 0);
    acc[1] = __builtin_amdgcn_mfma_f32_16x16x32_bf16(a, bc1, acc[1], 0, 0, 0);
    acc[2] = __builtin_amdgcn_mfma_f32_16x16x32_bf16(a, bc2, acc[2], 0, 0, 0);
    bc0 = bn0; bc1 = bn1; bc2 = bn2;
  }

  #pragma unroll
  for (int ni = 0; ni < 3; ni++){
    int col = colbase + ni * 16;
    float bw = (sel == 0) ? bW[col] : 0.f;
    #pragma unroll
    for (int r = 0; r < 4; r++){
      int grow = growb + hi * 4 + r;
      out[grow * H_ + col] = acc[ni][r] + bw;
    }
  }
}

// ---------------- phase 2: fused span GEMM + tanh + online softmax-pool ----------------
// R15 verbatim (spans structurally converged: serial-sum-of-pipes limit;
// all overlap mechanisms tested R2-R19 regress or tie).

__global__ __launch_bounds__(1024, 4)
void spans_fused(
    const unsigned short* __restrict__ hb,
    const float* __restrict__ Acoef,
    const float* __restrict__ Bcoef,
    const unsigned short* __restrict__ W4s,
    const float* __restrict__ hhat,
    const int* __restrict__ ii,
    const int* __restrict__ jj,
    float* __restrict__ pm, float* __restrict__ pl, float* __restrict__ pacc){
  __shared__ char As[TP * H_ * 2];       // 96 KiB swizzled product panel
  __shared__ int iis[TP], jjs[TP];
  __shared__ float sbuf[16][TP];
  __shared__ float wbuf[TP];

  const int bidraw = blockIdx.x;
  const int b = bidraw & 7;              // batch -> XCD affinity (scalar remap)
  const int tile = bidraw >> 3;          // 0..128
  const int bid = b * NBLK + tile;       // logical id for pm/pl/pacc
  const int p0 = tile * TP;
  const int tid = threadIdx.x;

  if (tid < TP){ iis[tid] = ii[p0 + tid]; jjs[tid] = jj[p0 + tid]; }
  __syncthreads();

  { // stage products h_i (.) h_j (bf16), k-interleaved: k = kk*128 + c*8
    int r = tid >> 4;      // 0..63 pair row
    int c = tid & 15;      // 0..15
    const unsigned short* hp = hb + (b * N_ + iis[r]) * H_;
    const unsigned short* hq = hb + (b * N_ + jjs[r]) * H_;
    #pragma unroll
    for (int kk = 0; kk < 6; kk++){
      int k = kk * 128 + c * 8;
      bf16x8 va = *(const bf16x8*)(hp + k);
      bf16x8 vb = *(const bf16x8*)(hq + k);
      *(bf16x8*)(As + lds_off(r, k)) = prodpack(va, vb);
    }
  }

  const int lane = tid & 63;
  const int wave = tid >> 6;     // 0..15 : 48-col group
  const int hi = lane >> 4;      // 0..3
  const int l15 = lane & 15;
  const int colbase = wave * 48 + l15;

  // accumulator init = Acoef[i,col] + Bcoef[j,col]  (MFMA C-in; overlaps staging)
  f32x4 acc[4][3];
  #pragma unroll
  for (int mi = 0; mi < 4; mi++){
    #pragma unroll
    for (int r = 0; r < 4; r++){
      int rowl = mi * 16 + hi * 4 + r;
      const float* ap = Acoef + (b * N_ + iis[rowl]) * H_ + colbase;
      const float* bp = Bcoef + (b * N_ + jjs[rowl]) * H_ + colbase;
      #pragma unroll
      for (int ni = 0; ni < 3; ni++)
        acc[mi][ni][r] = ap[ni * 16] + bp[ni * 16];
    }
  }

  // 3-slot B pipeline prologue: load steps 0 and 1
  const bf16x8* wp = (const bf16x8*)W4s + hi * H_ + colbase;
  bf16x8 bs[3][3];
  #pragma unroll
  for (int s = 0; s < 2; s++)
    #pragma unroll
    for (int ni = 0; ni < 3; ni++)
      bs[s][ni] = wp[s * 4 * H_ + ni * 16];

  __syncthreads();

  // ---- main K loop: fully unrolled so bs[t%3] indices are compile-time
  #pragma unroll
  for (int t = 0; t < NSTEP; ++t){
    // issue B loads for step t+2 (lead 2)
    if (t + 2 < NSTEP){
      #pragma unroll
      for (int ni = 0; ni < 3; ni++)
        bs[(t + 2) % 3][ni] = wp[(t + 2) * 4 * H_ + ni * 16];
    }
    const int kb = t * 32 + hi * 8;
    bf16x8 a0 = *(const bf16x8*)(As + lds_off(     l15, kb));
    bf16x8 a1 = *(const bf16x8*)(As + lds_off(16 + l15, kb));
    bf16x8 a2 = *(const bf16x8*)(As + lds_off(32 + l15, kb));
    bf16x8 a3 = *(const bf16x8*)(As + lds_off(48 + l15, kb));
    #pragma unroll
    for (int ni = 0; ni < 3; ni++){
      bf16x8 bfr = bs[t % 3][ni];
      acc[0][ni] = __builtin_amdgcn_mfma_f32_16x16x32_bf16(a0, bfr, acc[0][ni], 0, 0, 0);
      acc[1][ni] = __builtin_amdgcn_mfma_f32_16x16x32_bf16(a1, bfr, acc[1][ni], 0, 0, 0);
      acc[2][ni] = __builtin_amdgcn_mfma_f32_16x16x32_bf16(a2, bfr, acc[2][ni], 0, 0, 0);
      acc[3][ni] = __builtin_amdgcn_mfma_f32_16x16x32_bf16(a3, bfr, acc[3][ni], 0, 0, 0);
    }
  }

  // epilogue (pure VALU): spans = tanh(acc); score partials vs h_hat
  float sc[4][4];
  #pragma unroll
  for (int mi = 0; mi < 4; mi++)
    #pragma unroll
    for (int r = 0; r < 4; r++) sc[mi][r] = 0.f;

  #pragma unroll
  for (int ni = 0; ni < 3; ni++){
    float hh = hhat[colbase + ni * 16];
    #pragma unroll
    for (int mi = 0; mi < 4; mi++){
      #pragma unroll
      for (int r = 0; r < 4; r++){
        float s = tanh_fast(acc[mi][ni][r]);
        acc[mi][ni][r] = s;            // keep span in-register
        sc[mi][r] += s * hh;
      }
    }
  }
  // reduce score over the 16-lane column group
  #pragma unroll
  for (int mi = 0; mi < 4; mi++)
    #pragma unroll
    for (int r = 0; r < 4; r++){
      float v = sc[mi][r];
      v += __shfl_xor(v, 1); v += __shfl_xor(v, 2);
      v += __shfl_xor(v, 4); v += __shfl_xor(v, 8);
      sc[mi][r] = v;
    }
  if (l15 == 0){
    #pragma unroll
    for (int mi = 0; mi < 4; mi++)
      #pragma unroll
      for (int r = 0; r < 4; r++)
        sbuf[wave][mi * 16 + hi * 4 + r] = sc[mi][r];
  }
  __syncthreads();

  // block-local softmax weights (wave 0)
  if (tid < TP){
    float s = 0.f;
    #pragma unroll
    for (int w = 0; w < 16; w++) s += sbuf[w][tid];
    float m = s;
    #pragma unroll
    for (int off = 1; off < 64; off <<= 1) m = fmaxf(m, __shfl_xor(m, off));
    float w = __expf(s - m);
    float l = w;
    #pragma unroll
    for (int off = 1; off < 64; off <<= 1) l += __shfl_xor(l, off);
    wbuf[tid] = w;
    if (tid == 0){ pm[bid] = m; pl[bid] = l; }
  }
  __syncthreads();

  // weighted span accumulation -> pacc directly
  #pragma unroll
  for (int ni = 0; ni < 3; ni++){
    float wa = 0.f;
    #pragma unroll
    for (int mi = 0; mi < 4; mi++)
      #pragma unroll
      for (int r = 0; r < 4; r++){
        int rowl = mi * 16 + hi * 4 + r;
        wa += wbuf[rowl] * acc[mi][ni][r];
      }
    wa += __shfl_xor(wa, 16);
    wa += __shfl_xor(wa, 32);
    if (lane < 16) pacc[bid * H_ + colbase + ni * 16] = wa;
  }
}

// ---------------- phase 3: fused flash-merge + logits + log_softmax ----------------

__global__ void merge_kernel(
    const float* __restrict__ pm, const float* __restrict__ pl,
    const float* __restrict__ pacc,
    const float* __restrict__ Wout, const float* __restrict__ bout,
    float* __restrict__ outp){
  __shared__ float ebuf[NBLK];
  __shared__ float ht[H_];
  __shared__ float MLs[2];
  __shared__ float lg[C_];
  const int b = blockIdx.x;
  const int tid = threadIdx.x;   // 768

  if (tid < 64){
    float m = -3.4e38f;
    for (int t = tid; t < NBLK; t += 64) m = fmaxf(m, pm[b * NBLK + t]);
    #pragma unroll
    for (int off = 1; off < 64; off <<= 1) m = fmaxf(m, __shfl_xor(m, off));
    float l = 0.f;
    for (int t = tid; t < NBLK; t += 64) l += pl[b * NBLK + t] * __expf(pm[b * NBLK + t] - m);
    #pragma unroll
    for (int off = 1; off < 64; off <<= 1) l += __shfl_xor(l, off);
    if (tid == 0){ MLs[0] = m; MLs[1] = 1.f / l; }
  }
  __syncthreads();
  const float M = MLs[0], invL = MLs[1];
  if (tid < NBLK) ebuf[tid] = __expf(pm[b * NBLK + tid] - M);
  __syncthreads();
  { // one column per thread, coalesced pacc rows
    float a = 0.f;
    for (int t = 0; t < NBLK; t++) a += pacc[(b * NBLK + t) * H_ + tid] * ebuf[t];
    ht[tid] = a * invL;
  }
  __syncthreads();
  if (tid < C_ * 64){
    int c = tid >> 6; int lane = tid & 63;
    float a = 0.f;
    for (int k = lane; k < H_; k += 64) a += ht[k] * Wout[k * C_ + c];
    #pragma unroll
    for (int off = 1; off < 64; off <<= 1) a += __shfl_xor(a, off);
    if (lane == 0) lg[c] = a + bout[c];
  }
  __syncthreads();
  if (tid == 0){
    float mx = lg[0];
    #pragma unroll
    for (int c = 1; c < C_; c++) mx = fmaxf(mx, lg[c]);
    float s = 0.f;
    #pragma unroll
    for (int c = 0; c < C_; c++) s += __expf(lg[c] - mx);
    float ls = __logf(s) + mx;
    #pragma unroll
    for (int c = 0; c < C_; c++) outp[b * C_ + c] = lg[c] - ls;
  }
}

// ---------------- launch ----------------

extern "C" void kernel_launch(void* const* d_in, const int* in_sizes, int n_in,
                              void* d_out, int out_size, void* d_ws, size_t ws_size,
                              hipStream_t stream){
  const float* h    = (const float*)d_in[0];
  const float* Wcat = (const float*)d_in[1];
  const float* bW   = (const float*)d_in[2];
  const float* hhat = (const float*)d_in[3];
  const float* Wout = (const float*)d_in[4];
  const float* bout = (const float*)d_in[5];
  float* outp = (float*)d_out;

  // workspace carve-up (~14.7 MB total)
  unsigned short* hb   = (unsigned short*)d_ws;        // 786432 bf16
  unsigned short* Wsum = hb + 786432;                  // 589824 bf16 each
  unsigned short* Wdif = Wsum + 589824;
  unsigned short* W4s  = Wdif + 589824;
  float* Acoef = (float*)(W4s + 589824);               // 786432 f32
  float* Bcoef = Acoef + 786432;                       // 786432 f32
  int* iiA = (int*)(Bcoef + 786432);                   // 8256 i32
  int* jjA = iiA + P_;
  float* pm = (float*)(jjA + P_);                      // 1032 f32
  float* pl = pm + (B_ * NBLK);
  float* pacc = pl + (B_ * NBLK);                      // 1032*768 f32

  prep<<<PH_BLKS + PW_BLKS + PR_BLKS, 256, 0, stream>>>(h, Wcat, hb, Wsum, Wdif, W4s, iiA, jjA);
  coef_gemm<<<dim3(64, 2, 2), 512, 0, stream>>>(hb, Wsum, Wdif, bW, Acoef, Bcoef);
  spans_fused<<<B_ * NBLK, 1024, 0, stream>>>(hb, Acoef, Bcoef, W4s, hhat, iiA, jjA, pm, pl, pacc);
  merge_kernel<<<B_, 768, 0, stream>>>(pm, pl, pacc, Wout, bout, outp);
}